// Round 11
// baseline (2295.985 us; speedup 1.0000x reference)
//
#include <hip/hip_runtime.h>
#include <math.h>

#define Nn 200000
#define NNZV 6400000
#define NE 500000
#define HID 256
#define LAT 128

typedef _Float16 h2 __attribute__((ext_vector_type(2)));
typedef _Float16 f16x4 __attribute__((ext_vector_type(4)));
typedef _Float16 f16x8 __attribute__((ext_vector_type(8)));
typedef float f32x4 __attribute__((ext_vector_type(4)));
typedef short s16x8 __attribute__((ext_vector_type(8)));
struct alignas(8) H4 { _Float16 h[4]; };

// ---------------- CSR build ----------------
__global__ __launch_bounds__(256) void k_zero(int* __restrict__ cnt){
  int i = blockIdx.x*256 + threadIdx.x;
  if(i < Nn) cnt[i] = 0;
}

__global__ __launch_bounds__(256) void k_count(const int* __restrict__ rows, int* __restrict__ cnt){
  int i = blockIdx.x*256 + threadIdx.x;
  if(i < NNZV) atomicAdd(&cnt[rows[i]], 1);
}

__global__ __launch_bounds__(512) void k_scan_block(const int* __restrict__ cnt, int* __restrict__ incl, int* __restrict__ bsum){
  __shared__ int s[512];
  int t = threadIdx.x;
  int i = blockIdx.x*512 + t;
  int v = (i < Nn) ? cnt[i] : 0;
  s[t] = v; __syncthreads();
  for(int off = 1; off < 512; off <<= 1){
    int x = (t >= off) ? s[t-off] : 0;
    __syncthreads();
    s[t] += x;
    __syncthreads();
  }
  if(i < Nn) incl[i] = s[t];
  if(t == 511) bsum[blockIdx.x] = s[t];
}

__global__ __launch_bounds__(512) void k_scan_bsum(int* __restrict__ bsum, int nb){
  __shared__ int s[512];
  int t = threadIdx.x;
  int v = (t < nb) ? bsum[t] : 0;
  s[t] = v; __syncthreads();
  for(int off = 1; off < 512; off <<= 1){
    int x = (t >= off) ? s[t-off] : 0;
    __syncthreads();
    s[t] += x;
    __syncthreads();
  }
  if(t < nb) bsum[t] = s[t] - v;
}

// writes row_ptr AND initializes cur
__global__ __launch_bounds__(256) void k_finish(const int* __restrict__ incl, const int* __restrict__ boff,
                                                int* __restrict__ row_ptr, int* __restrict__ cur){
  int i = blockIdx.x*256 + threadIdx.x;
  if(i < Nn){
    int v = incl[i] + boff[i >> 9];
    row_ptr[i+1] = v;
    if(i < Nn-1) cur[i+1] = v;
  }
  if(i == 0){ row_ptr[0] = 0; cur[0] = 0; }
}

__global__ __launch_bounds__(256) void k_scatter(const int* __restrict__ rows, const int* __restrict__ cols,
    const float* __restrict__ vals, int* __restrict__ cur,
    int* __restrict__ cols_s, _Float16* __restrict__ vals_s){
  int i = blockIdx.x*256 + threadIdx.x;
  if(i >= NNZV) return;
  int r = rows[i];
  int j = atomicAdd(&cur[r], 1);
  cols_s[j] = cols[i];
  vals_s[j] = (_Float16)vals[i];
}

// ---------------- feature pack ----------------
// logical cols [0,144): [xp(0..61) | xf(62..98) | pad99 | xn(100..136) | pad..143]
__global__ __launch_bounds__(256) void k_xpack(const float* __restrict__ xp, const float* __restrict__ xf,
    const float* __restrict__ xn, _Float16* __restrict__ xc0, _Float16* __restrict__ xtl){
  int idx = blockIdx.x*256 + threadIdx.x;   // N*18 chunks of 8 cols
  int row = idx/18, c8 = idx - row*18;
  if(row >= Nn) return;
  H4 ha, hb;
  #pragma unroll
  for(int q = 0; q < 8; q++){
    int c = c8*8 + q;
    float x;
    if(c < 62)       x = xp[row*62 + c];
    else if(c < 99)  x = xf[row*37 + (c-62)];
    else if(c == 99) x = 0.f;
    else if(c < 137) x = xn[row*37 + (c-100)];
    else             x = 0.f;
    if(q < 4) ha.h[q] = (_Float16)x; else hb.h[q-4] = (_Float16)x;
  }
  if(c8 < 16){
    *(H4*)&xc0[(size_t)row*128 + c8*8]     = ha;
    *(H4*)&xc0[(size_t)row*128 + c8*8 + 4] = hb;
  } else {
    int t = (c8-16)*8;
    *(H4*)&xtl[(size_t)row*16 + t]     = ha;
    *(H4*)&xtl[(size_t)row*16 + t + 4] = hb;
  }
}

// ---------------- weight pack into MFMA B-fragment order ----------------
__global__ __launch_bounds__(256) void k_wpackF(
    const float* __restrict__ Wp1, const float* __restrict__ Wf1, const float* __restrict__ Wn1,
    const float* __restrict__ Wp2, const float* __restrict__ Wf2, const float* __restrict__ Wn2,
    _Float16* __restrict__ w1fp, _Float16* __restrict__ w1ff, _Float16* __restrict__ w1fn,
    _Float16* __restrict__ w2fp, _Float16* __restrict__ w2ff, _Float16* __restrict__ w2fn){
  int i = blockIdx.x*256 + threadIdx.x;
  if(i >= 18432) return;
  int v = i / 6144, rem = i - v*6144;
  const float* W1 = (v==0)?Wp1:((v==1)?Wf1:Wn1);
  const float* W2 = (v==0)?Wp2:((v==1)?Wf2:Wn2);
  _Float16* d1 = (v==0)?w1fp:((v==1)?w1ff:w1fn);
  _Float16* d2 = (v==0)?w2fp:((v==1)?w2ff:w2fn);
  int Kv = (v==0)?62:37;
  f16x8 o;
  if(rem < 2048){
    int kt = rem >> 10, r2 = rem & 1023;
    int nt = r2 >> 6, l = r2 & 63;
    int krow = kt*32 + (l>>4)*8, col = nt*16 + (l&15);
    #pragma unroll
    for(int j = 0; j < 8; j++){
      int k = krow + j;
      o[j] = (k < Kv) ? (_Float16)W1[k*256 + col] : (_Float16)0.f;
    }
    *(f16x8*)&d1[rem*8] = o;
  } else {
    int r = rem - 2048;
    int kt = r >> 9, nt = (r >> 6) & 7, l = r & 63;
    int krow = kt*32 + (l>>4)*8, col = nt*16 + (l&15);
    #pragma unroll
    for(int j = 0; j < 8; j++)
      o[j] = (_Float16)W2[(krow + j)*128 + col];
    *(f16x8*)&d2[r*8] = o;
  }
}

// ---------------- wg2[v][256] = W2v @ Wgv (gate fold to hidden space) ----------------
__global__ void k_wg2(const float* __restrict__ Wp2, const float* __restrict__ Wgp,
                      const float* __restrict__ Wf2, const float* __restrict__ Wgf,
                      const float* __restrict__ Wn2, const float* __restrict__ Wgn,
                      float* __restrict__ wg2){
  int k = threadIdx.x;   // 256
  float p = 0.f, f = 0.f, n = 0.f;
  for(int c = 0; c < 128; c++){
    p = fmaf(Wp2[k*128 + c], Wgp[c], p);
    f = fmaf(Wf2[k*128 + c], Wgf[c], f);
    n = fmaf(Wn2[k*128 + c], Wgn[c], n);
  }
  wg2[k] = p; wg2[256 + k] = f; wg2[512 + k] = n;
}

// ---------------- gate-score constants: c_v = dot(b2_v, Wg_v) + bg_v ----------------
__global__ void k_const(const float* b2p, const float* Wgp, const float* bgp,
                        const float* b2f, const float* Wgf, const float* bgf,
                        const float* b2n, const float* Wgn, const float* bgn,
                        float* c3){
  int l = threadIdx.x;
  float p = 0.f, f = 0.f, n = 0.f;
  for(int j = l; j < LAT; j += 64){
    p += b2p[j]*Wgp[j];
    f += b2f[j]*Wgf[j];
    n += b2n[j]*Wgn[j];
  }
  #pragma unroll
  for(int off = 32; off >= 1; off >>= 1){
    p += __shfl_xor(p, off);
    f += __shfl_xor(f, off);
    n += __shfl_xor(n, off);
  }
  if(l == 0){ c3[0] = p + bgp[0]; c3[1] = f + bgf[0]; c3[2] = n + bgn[0]; }
}

// ---------------- MFMA encoder view ----------------
__device__ __forceinline__ void encode_view(
    int tid, int row0, int voff, int Kv, int vidx,
    const _Float16 (*sT)[152], _Float16 (*sTv)[72], _Float16 (*hT)[264],
    const _Float16* __restrict__ w1frag, const float* __restrict__ b1,
    const _Float16* __restrict__ w2frag, const float* __restrict__ wg2v,
    _Float16* __restrict__ Y3, float* __restrict__ yg4f){
  int w = tid >> 6, l = tid & 63;
  int kg = l >> 4, er = l & 15;
  int mrow = (w & 1)*16 + er;

  // phase A: aligned, zero-padded A-tile
  {
    int row = tid >> 3, c0 = (tid & 7)*8;
    f16x8 vv;
    #pragma unroll
    for(int q = 0; q < 8; q++){
      int c = c0 + q;
      vv[q] = (c < Kv) ? sT[row][voff + c] : (_Float16)0.f;
    }
    *(f16x8*)&sTv[row][c0] = vv;
  }
  __syncthreads();

  // phase B: G1 = sTv[32x64] @ W1[64x256] -> relu -> hT fp16
  {
    f16x8 a0 = *(const f16x8*)&sTv[mrow][kg*8];
    f16x8 a1 = *(const f16x8*)&sTv[mrow][32 + kg*8];
    int ntb = (w >> 1)*8;
    #pragma unroll
    for(int nt8 = 0; nt8 < 8; nt8++){
      int nt = ntb + nt8;
      f16x8 b0 = *(const f16x8*)&w1frag[(size_t)((0*16 + nt)*64 + l)*8];
      f16x8 b1v = *(const f16x8*)&w1frag[(size_t)((1*16 + nt)*64 + l)*8];
      f32x4 acc = {0.f, 0.f, 0.f, 0.f};
      acc = __builtin_amdgcn_mfma_f32_16x16x32_f16(a0, b0, acc, 0, 0, 0);
      acc = __builtin_amdgcn_mfma_f32_16x16x32_f16(a1, b1v, acc, 0, 0, 0);
      int col = nt*16 + er;
      float bb = b1[col];
      #pragma unroll
      for(int j = 0; j < 4; j++)
        hT[(w & 1)*16 + kg*4 + j][col] = (_Float16)fmaxf(acc[j] + bb, 0.f);
    }
  }
  __syncthreads();

  // phase C: gate partial  yg = hT . wg2
  {
    int row = tid >> 3, cg = tid & 7;
    float p = 0.f;
    #pragma unroll 8
    for(int kk = 0; kk < 32; kk++)
      p = fmaf((float)hT[row][cg*32 + kk], wg2v[cg*32 + kk], p);
    p += __shfl_xor(p, 1);
    p += __shfl_xor(p, 2);
    p += __shfl_xor(p, 4);
    if((tid & 7) == 0) yg4f[(size_t)(row0 + row)*4 + vidx] = p;
  }

  // phase D: G2 = hT[32x256] @ W2[256x128] -> LDS stage -> Y3 (coalesced 16B stores)
  {
    f16x8 af[8];
    #pragma unroll
    for(int kt = 0; kt < 8; kt++)
      af[kt] = *(const f16x8*)&hT[mrow][kt*32 + kg*8];
    __syncthreads();            // all hT reads done -> hT reusable as Y stage
    _Float16* yst = &hT[0][0];  // viewed as [32][132]
    int ntb = (w >> 1)*4;
    #pragma unroll
    for(int nt4 = 0; nt4 < 4; nt4++){
      int nt = ntb + nt4;
      f32x4 acc = {0.f, 0.f, 0.f, 0.f};
      #pragma unroll
      for(int kt = 0; kt < 8; kt++){
        f16x8 bf = *(const f16x8*)&w2frag[(size_t)((kt*8 + nt)*64 + l)*8];
        acc = __builtin_amdgcn_mfma_f32_16x16x32_f16(af[kt], bf, acc, 0, 0, 0);
      }
      int col = nt*16 + er;
      #pragma unroll
      for(int j = 0; j < 4; j++)
        yst[((w & 1)*16 + kg*4 + j)*132 + col] = (_Float16)acc[j];
    }
    __syncthreads();
    int row = tid >> 3, c0 = (tid & 7)*16;
    f16x8 y0 = *(const f16x8*)&yst[row*132 + c0];
    f16x8 y1 = *(const f16x8*)&yst[row*132 + c0 + 8];
    _Float16* yo = &Y3[(size_t)(row0 + row)*384 + vidx*128 + c0];
    *(f16x8*)yo       = y0;
    *(f16x8*)(yo + 8) = y1;
  }
  __syncthreads();   // hT/sTv reused by next view
}

// ---------------- fused spmm1 (2 rows/wave) + 3 MFMA encoders ----------------
__global__ __launch_bounds__(256, 5) void k_encfused(
    const int* __restrict__ row_ptr, const int* __restrict__ cols_s, const _Float16* __restrict__ vals_s,
    const _Float16* __restrict__ xc0, const _Float16* __restrict__ xtl,
    const _Float16* __restrict__ w1fp, const float* __restrict__ bp1, const _Float16* __restrict__ w2fp,
    const _Float16* __restrict__ w1ff, const float* __restrict__ bf1, const _Float16* __restrict__ w2ff,
    const _Float16* __restrict__ w1fn, const float* __restrict__ bn1, const _Float16* __restrict__ w2fn,
    const float* __restrict__ wg2,
    _Float16* __restrict__ Y3, float* __restrict__ yg4f){
  __shared__ _Float16 sT[32][152];   // 9.5 KB
  __shared__ _Float16 sTv[32][72];   // 4.5 KB
  __shared__ _Float16 hT[32][264];   // 16.5 KB (reused as Y stage in phase D)
  int tid = threadIdx.x;
  int lane = tid & 63, wid = tid >> 6;
  int hl = lane & 31;
  int half = lane >> 5;
  int base = lane & 32;
  int row0 = blockIdx.x * 32;
  bool hast = (hl < 4);
  const char* xc0b = (const char*)xc0;
  const char* xtlb = (const char*)xtl;

  // phase 0: gather-spmm, 2 rows per wave (half-wave per row).
  for(int p = 0; p < 4; p++){
    int rr = wid*8 + p*2 + half;
    int r = row0 + rr;
    int start = row_ptr[r], end = row_ptr[r+1];
    int len = end - start;
    int lenO = __shfl(len, lane ^ 32);
    int lenmax = len > lenO ? len : lenO;
    float a0 = 0.f, a1 = 0.f, a2 = 0.f, a3 = 0.f;
    float t0 = 0.f, t1 = 0.f, t2 = 0.f, t3 = 0.f;
    for(int j0 = 0; j0 < lenmax; j0 += 32){
      int m = len - j0; if(m > 32) m = 32; if(m < 0) m = 0;
      int mO = lenO - j0; if(mO > 32) mO = 32; if(mO < 0) mO = 0;
      int mmax = m > mO ? m : mO;
      int mycol = 0; float myval = 0.f;
      if(hl < m){
        mycol = cols_s[start + j0 + hl];
        myval = (float)vals_s[start + j0 + hl];
      }
      int mpad = (mmax + 3) & ~3;
      for(int k = 0; k < mpad; k += 4){
        #pragma unroll
        for(int q = 0; q < 4; q++){
          int c = __shfl(mycol, base + k + q);
          float v = __shfl(myval, base + k + q);
          f16x4 xa = *(const f16x4*)(xc0b + (((unsigned)c) << 8) + hl*8);
          a0 = fmaf((float)xa[0], v, a0);
          a1 = fmaf((float)xa[1], v, a1);
          a2 = fmaf((float)xa[2], v, a2);
          a3 = fmaf((float)xa[3], v, a3);
          if(hast){
            f16x4 xb = *(const f16x4*)(xtlb + ((unsigned)c)*32u + hl*8);
            t0 = fmaf((float)xb[0], v, t0);
            t1 = fmaf((float)xb[1], v, t1);
            t2 = fmaf((float)xb[2], v, t2);
            t3 = fmaf((float)xb[3], v, t3);
          }
        }
      }
    }
    h2 s01; s01[0] = (_Float16)a0; s01[1] = (_Float16)a1;
    h2 s23; s23[0] = (_Float16)a2; s23[1] = (_Float16)a3;
    *(h2*)&sT[rr][4*hl]     = s01;
    *(h2*)&sT[rr][4*hl + 2] = s23;
    if(hast){
      h2 u01; u01[0] = (_Float16)t0; u01[1] = (_Float16)t1;
      h2 u23; u23[0] = (_Float16)t2; u23[1] = (_Float16)t3;
      *(h2*)&sT[rr][128 + 4*hl]     = u01;
      *(h2*)&sT[rr][128 + 4*hl + 2] = u23;
    }
  }
  __syncthreads();

  encode_view(tid, row0, 0,   62, 0, sT, sTv, hT, w1fp, bp1, w2fp, wg2,       Y3, yg4f);
  encode_view(tid, row0, 62,  37, 1, sT, sTv, hT, w1ff, bf1, w2ff, wg2 + 256, Y3, yg4f);
  encode_view(tid, row0, 100, 37, 2, sT, sTv, hT, w1fn, bn1, w2fn, wg2 + 512, Y3, yg4f);
}

// ---------------- gate-score spmm + softmax -> alpha[N] (float4) ----------------
// sc_v[r] = sum_c A[r,c]*yg_v[c] + c3[v]; yg table is 3.2 MB (L2-resident)
__global__ __launch_bounds__(256, 8) void k_score(
    const int* __restrict__ row_ptr, const int* __restrict__ cols_s, const _Float16* __restrict__ vals_s,
    const float4* __restrict__ yg4, const float* __restrict__ c3,
    float4* __restrict__ alpha){
  int tid = threadIdx.x;
  int lane = tid & 63;
  int hl = lane & 31;
  int half = lane >> 5;
  int r = blockIdx.x*8 + (tid >> 6)*2 + half;
  int start = row_ptr[r], end = row_ptr[r+1];
  int len = end - start;
  float scp = 0.f, scf = 0.f, scn = 0.f;
  for(int j0 = hl; j0 < len; j0 += 32){
    int c = cols_s[start + j0];
    float v = (float)vals_s[start + j0];
    float4 g = yg4[c];
    scp = fmaf(v, g.x, scp);
    scf = fmaf(v, g.y, scf);
    scn = fmaf(v, g.z, scn);
  }
  #pragma unroll
  for(int off = 16; off >= 1; off >>= 1){
    scp += __shfl_xor(scp, off);
    scf += __shfl_xor(scf, off);
    scn += __shfl_xor(scn, off);
  }
  if(hl == 0){
    float sp = scp + c3[0], sf = scf + c3[1], sn = scn + c3[2];
    float mx = fmaxf(sp, fmaxf(sf, sn));
    float ep = expf(sp - mx), ef = expf(sf - mx), en = expf(sn - mx);
    float inv = 1.f / (ep + ef + en);
    alpha[r] = make_float4(ep*inv, ef*inv, en*inv, 0.f);
  }
}

// ---------------- spmm2 half-pass: z[:, H*64:(H+1)*64] (77 MB working set -> L3-resident) ----------------
template<int H>
__global__ __launch_bounds__(256, 8) void k_spmm2h(
    const int* __restrict__ row_ptr, const int* __restrict__ cols_s, const _Float16* __restrict__ vals_s,
    const _Float16* __restrict__ Y3, const float4* __restrict__ alpha,
    const float* __restrict__ b2p, const float* __restrict__ b2f, const float* __restrict__ b2n,
    _Float16* __restrict__ z){
  int tid = threadIdx.x;
  int lane = tid & 63;
  int hl = lane & 31;
  int half = lane >> 5;
  int base = lane & 32;
  int r = blockIdx.x*8 + (tid >> 6)*2 + half;   // 8 rows/block
  int start = row_ptr[r], end = row_ptr[r+1];
  int len = end - start;
  int lenO = __shfl(len, lane ^ 32);
  int lenmax = len > lenO ? len : lenO;
  unsigned lo = H*128 + hl*4;            // byte offset within 256 B view row (2 cols of this half)
  float ap0=0.f, ap1=0.f, af0=0.f, af1=0.f, an0=0.f, an1=0.f;
  const char* Yb = (const char*)Y3;
  for(int j0 = 0; j0 < lenmax; j0 += 32){
    int m = len - j0; if(m > 32) m = 32; if(m < 0) m = 0;
    int mO = lenO - j0; if(mO > 32) mO = 32; if(mO < 0) mO = 0;
    int mmax = m > mO ? m : mO;
    int mycol = 0; float myval = 0.f;
    if(hl < m){
      mycol = cols_s[start + j0 + hl];
      myval = (float)vals_s[start + j0 + hl];
    }
    int mpad = (mmax + 3) & ~3;
    for(int k = 0; k < mpad; k += 4){
      #pragma unroll
      for(int q = 0; q < 4; q++){
        int c = __shfl(mycol, base + k + q);
        float v = __shfl(myval, base + k + q);
        const char* p = Yb + ((unsigned)c)*768u + lo;
        h2 yp = *(const h2*)(p);
        h2 yf = *(const h2*)(p + 256);
        h2 yn = *(const h2*)(p + 512);
        ap0 = fmaf((float)yp[0], v, ap0); ap1 = fmaf((float)yp[1], v, ap1);
        af0 = fmaf((float)yf[0], v, af0); af1 = fmaf((float)yf[1], v, af1);
        an0 = fmaf((float)yn[0], v, an0); an1 = fmaf((float)yn[1], v, an1);
      }
    }
  }
  float4 al = alpha[r];
  int o = H*64 + hl*2;
  float2 bp = *(const float2*)&b2p[o];
  float2 bf = *(const float2*)&b2f[o];
  float2 bn = *(const float2*)&b2n[o];
  float z0 = al.x*(ap0 + bp.x) + al.y*(af0 + bf.x) + al.z*(an0 + bn.x);
  float z1 = al.x*(ap1 + bp.y) + al.y*(af1 + bf.y) + al.z*(an1 + bn.y);
  h2 uz; uz[0] = (_Float16)z0; uz[1] = (_Float16)z1;
  *(h2*)&z[(size_t)r*LAT + o] = uz;
}

// ---------------- edge decoder: MFMA, wave = feature region ----------------
#define DEC_TILES (NE/16)
__global__ __launch_bounds__(256) void k_dec(
    const _Float16* __restrict__ z, const int* __restrict__ esrc, const int* __restrict__ edst,
    const float* __restrict__ Wd1, const float* __restrict__ bd1,
    const float* __restrict__ Wd2, const float* __restrict__ bd2, float* __restrict__ out){
  __shared__ float part[4][16][68];   // 17.4 KB
  int tid = threadIdx.x;
  int w  = tid >> 6;
  int l  = tid & 63;
  int erow = l & 15;
  int kg   = l >> 4;

  f16x8 bfr[4][4];
  #pragma unroll
  for(int kt = 0; kt < 4; kt++){
    #pragma unroll
    for(int nt = 0; nt < 4; nt++){
      f16x8 bb;
      #pragma unroll
      for(int j = 0; j < 8; j++)
        bb[j] = (_Float16)Wd1[(w*128 + kt*32 + kg*8 + j)*64 + nt*16 + erow];
      bfr[kt][nt] = bb;
    }
  }

  int n0 = (tid & 15) * 4;
  int e2 = tid >> 4;
  float4 bb1 = *(const float4*)&bd1[n0];
  float4 w2v = *(const float4*)&Wd2[n0];
  float bias2 = bd2[0];

  for(int tile = blockIdx.x; tile < DEC_TILES; tile += gridDim.x){
    int e = tile*16 + erow;
    int si = esrc[e], di = edst[e];
    const f16x8* zs = (const f16x8*)&z[(size_t)si*LAT];
    const f16x8* zd = (const f16x8*)&z[(size_t)di*LAT];
    f16x8 afr[4];
    if(w == 0){
      #pragma unroll
      for(int kt = 0; kt < 4; kt++) afr[kt] = zs[kt*4 + kg];
    } else if(w == 1){
      #pragma unroll
      for(int kt = 0; kt < 4; kt++) afr[kt] = zd[kt*4 + kg];
    } else if(w == 2){
      #pragma unroll
      for(int kt = 0; kt < 4; kt++) afr[kt] = zs[kt*4 + kg] * zd[kt*4 + kg];
    } else {
      #pragma unroll
      for(int kt = 0; kt < 4; kt++){
        f16x8 d = zs[kt*4 + kg] - zd[kt*4 + kg];
        s16x8 m = __builtin_bit_cast(s16x8, d) & (short)0x7fff;
        afr[kt] = __builtin_bit_cast(f16x8, m);
      }
    }
    f32x4 zero = {0.f, 0.f, 0.f, 0.f};
    f32x4 acc[4] = {zero, zero, zero, zero};
    #pragma unroll
    for(int kt = 0; kt < 4; kt++){
      #pragma unroll
      for(int nt = 0; nt < 4; nt++)
        acc[nt] = __builtin_amdgcn_mfma_f32_16x16x32_f16(afr[kt], bfr[kt][nt], acc[nt], 0, 0, 0);
    }
    #pragma unroll
    for(int nt = 0; nt < 4; nt++){
      #pragma unroll
      for(int j = 0; j < 4; j++)
        part[w][kg*4 + j][nt*16 + erow] = acc[nt][j];
    }
    __syncthreads();
    float s0 = part[0][e2][n0+0] + part[1][e2][n0+0] + part[2][e2][n0+0] + part[3][e2][n0+0];
    float s1 = part[0][e2][n0+1] + part[1][e2][n0+1] + part[2][e2][n0+1] + part[3][e2][n0+1];
    float s2 = part[0][e2][n0+2] + part[1][e2][n0+2] + part[2][e2][n0+2] + part[3][e2][n0+2];
    float s3 = part[0][e2][n0+3] + part[1][e2][n0+3] + part[2][e2][n0+3] + part[3][e2][n0+3];
    float p = fmaxf(s0 + bb1.x, 0.f)*w2v.x + fmaxf(s1 + bb1.y, 0.f)*w2v.y
            + fmaxf(s2 + bb1.z, 0.f)*w2v.z + fmaxf(s3 + bb1.w, 0.f)*w2v.w;
    #pragma unroll
    for(int off = 1; off < 16; off <<= 1) p += __shfl_xor(p, off);
    if((tid & 15) == 0) out[tile*16 + e2] = p + bias2;
    __syncthreads();
  }
}

// ---------------- host ----------------
extern "C" void kernel_launch(void* const* d_in, const int* in_sizes, int n_in,
                              void* d_out, int out_size, void* d_ws, size_t ws_size,
                              hipStream_t stream) {
  const float* xp  = (const float*)d_in[0];
  const float* xf  = (const float*)d_in[1];
  const float* xn  = (const float*)d_in[2];
  const int* arows = (const int*)d_in[3];
  const int* acols = (const int*)d_in[4];
  const float* avals = (const float*)d_in[5];
  const int* esrc  = (const int*)d_in[6];
  const int* edst  = (const int*)d_in[7];
  const float* Wp1 = (const float*)d_in[8];  const float* bp1 = (const float*)d_in[9];
  const float* Wp2 = (const float*)d_in[10]; const float* bp2 = (const float*)d_in[11];
  const float* Wf1 = (const float*)d_in[12]; const float* bf1 = (const float*)d_in[13];
  const float* Wf2 = (const float*)d_in[14]; const float* bf2w = (const float*)d_in[15];
  const float* Wn1 = (const float*)d_in[16]; const float* bn1 = (const float*)d_in[17];
  const float* Wn2 = (const float*)d_in[18]; const float* bn2 = (const float*)d_in[19];
  const float* Wgp = (const float*)d_in[20]; const float* bgp = (const float*)d_in[21];
  const float* Wgf = (const float*)d_in[22]; const float* bgf = (const float*)d_in[23];
  const float* Wgn = (const float*)d_in[24]; const float* bgn = (const float*)d_in[25];
  const float* Wd1 = (const float*)d_in[26]; const float* bd1 = (const float*)d_in[27];
  const float* Wd2 = (const float*)d_in[28]; const float* bd2 = (const float*)d_in[29];
  float* out = (float*)d_out;
  (void)in_sizes; (void)n_in; (void)out_size; (void)ws_size;

  char* base = (char*)d_ws;
  size_t off = 0;
  auto alloc = [&](size_t nbytes) -> char* {
    off = (off + 255) & ~(size_t)255;
    char* p = base + off;
    off += nbytes;
    return p;
  };
  int*      row_ptr = (int*)     alloc((size_t)(Nn + 1) * 4);   // 0.8 MB
  int*      cols_s  = (int*)     alloc((size_t)NNZV * 4);       // 25.6 MB
  _Float16* vals_s  = (_Float16*)alloc((size_t)NNZV * 2);       // 12.8 MB
  _Float16* xcat0   = (_Float16*)alloc((size_t)Nn * 128 * 2);   // 51.2 MB
  _Float16* xtail   = (_Float16*)alloc((size_t)Nn * 16 * 2);    // 6.4 MB
  _Float16* Y3      = (_Float16*)alloc((size_t)Nn * 384 * 2);   // 153.6 MB interleaved [N][3][128]
  float*    yg4     = (float*)   alloc((size_t)Nn * 4 * 4);     // 3.2 MB
  float*    c3      = (float*)   alloc(256);
  float*    wg2     = (float*)   alloc(3 * 256 * 4);
  _Float16* w1fp = (_Float16*)alloc(16384*2);
  _Float16* w1ff = (_Float16*)alloc(16384*2);
  _Float16* w1fn = (_Float16*)alloc(16384*2);
  _Float16* w2fp = (_Float16*)alloc(32768*2);
  _Float16* w2ff = (_Float16*)alloc(32768*2);
  _Float16* w2fn = (_Float16*)alloc(32768*2);
  // aliases: z -> xcat0 (dead after encfused); alpha -> xtail (dead after encfused);
  // CSR temps -> xcat0 (dead before k_xpack)
  _Float16* z     = xcat0;
  float4*   alpha = (float4*)xtail;
  int* cur  = (int*)((char*)xcat0);
  int* incl = (int*)((char*)xcat0 + 1000000);
  int* bsum = (int*)((char*)xcat0 + 2000000);
  // total ws: ~254 MB

  int NB = (Nn + 511) / 512;

  k_zero   <<<(Nn + 255)/256, 256, 0, stream>>>(cur);
  k_count  <<<(NNZV + 255)/256, 256, 0, stream>>>(arows, cur);
  k_scan_block<<<NB, 512, 0, stream>>>(cur, incl, bsum);
  k_scan_bsum<<<1, 512, 0, stream>>>(bsum, NB);
  k_finish <<<(Nn + 255)/256, 256, 0, stream>>>(incl, bsum, row_ptr, cur);
  k_scatter<<<(NNZV + 255)/256, 256, 0, stream>>>(arows, acols, avals, cur, cols_s, vals_s);

  k_xpack<<<(Nn*18 + 255)/256, 256, 0, stream>>>(xp, xf, xn, xcat0, xtail);
  k_wpackF<<<72, 256, 0, stream>>>(Wp1, Wf1, Wn1, Wp2, Wf2, Wn2,
                                   w1fp, w1ff, w1fn, w2fp, w2ff, w2fn);
  k_wg2<<<1, 256, 0, stream>>>(Wp2, Wgp, Wf2, Wgf, Wn2, Wgn, wg2);
  k_const<<<1, 64, 0, stream>>>(bp2, Wgp, bgp, bf2w, Wgf, bgf, bn2, Wgn, bgn, c3);

  k_encfused<<<Nn/32, 256, 0, stream>>>(row_ptr, cols_s, vals_s, xcat0, xtail,
      w1fp, bp1, w2fp,  w1ff, bf1, w2ff,  w1fn, bn1, w2fn,  wg2,
      Y3, yg4);

  k_score<<<Nn/8, 256, 0, stream>>>(row_ptr, cols_s, vals_s,
      (const float4*)yg4, c3, alpha);

  k_spmm2h<0><<<Nn/8, 256, 0, stream>>>(row_ptr, cols_s, vals_s, Y3, alpha,
      bp2, bf2w, bn2, z);
  k_spmm2h<1><<<Nn/8, 256, 0, stream>>>(row_ptr, cols_s, vals_s, Y3, alpha,
      bp2, bf2w, bn2, z);

  k_dec<<<2048, 256, 0, stream>>>(z, esrc, edst, Wd1, bd1, Wd2, bd2, out);
}

// Round 12
// 2094.335 us; speedup vs baseline: 1.0963x; 1.0963x over previous
//
#include <hip/hip_runtime.h>
#include <math.h>

#define Nn 200000
#define NNZV 6400000
#define NE 500000
#define HID 256
#define LAT 128

typedef _Float16 h2 __attribute__((ext_vector_type(2)));
typedef _Float16 f16x4 __attribute__((ext_vector_type(4)));
typedef _Float16 f16x8 __attribute__((ext_vector_type(8)));
typedef float f32x4 __attribute__((ext_vector_type(4)));
typedef short s16x8 __attribute__((ext_vector_type(8)));
struct alignas(8) H4 { _Float16 h[4]; };

// ---------------- CSR build ----------------
__global__ __launch_bounds__(256) void k_zero(int* __restrict__ cnt){
  int i = blockIdx.x*256 + threadIdx.x;
  if(i < Nn) cnt[i] = 0;
}

__global__ __launch_bounds__(256) void k_count(const int* __restrict__ rows, int* __restrict__ cnt){
  int i = blockIdx.x*256 + threadIdx.x;
  if(i < NNZV) atomicAdd(&cnt[rows[i]], 1);
}

__global__ __launch_bounds__(512) void k_scan_block(const int* __restrict__ cnt, int* __restrict__ incl, int* __restrict__ bsum){
  __shared__ int s[512];
  int t = threadIdx.x;
  int i = blockIdx.x*512 + t;
  int v = (i < Nn) ? cnt[i] : 0;
  s[t] = v; __syncthreads();
  for(int off = 1; off < 512; off <<= 1){
    int x = (t >= off) ? s[t-off] : 0;
    __syncthreads();
    s[t] += x;
    __syncthreads();
  }
  if(i < Nn) incl[i] = s[t];
  if(t == 511) bsum[blockIdx.x] = s[t];
}

__global__ __launch_bounds__(512) void k_scan_bsum(int* __restrict__ bsum, int nb){
  __shared__ int s[512];
  int t = threadIdx.x;
  int v = (t < nb) ? bsum[t] : 0;
  s[t] = v; __syncthreads();
  for(int off = 1; off < 512; off <<= 1){
    int x = (t >= off) ? s[t-off] : 0;
    __syncthreads();
    s[t] += x;
    __syncthreads();
  }
  if(t < nb) bsum[t] = s[t] - v;
}

// writes row_ptr AND initializes cur
__global__ __launch_bounds__(256) void k_finish(const int* __restrict__ incl, const int* __restrict__ boff,
                                                int* __restrict__ row_ptr, int* __restrict__ cur){
  int i = blockIdx.x*256 + threadIdx.x;
  if(i < Nn){
    int v = incl[i] + boff[i >> 9];
    row_ptr[i+1] = v;
    if(i < Nn-1) cur[i+1] = v;
  }
  if(i == 0){ row_ptr[0] = 0; cur[0] = 0; }
}

__global__ __launch_bounds__(256) void k_scatter(const int* __restrict__ rows, const int* __restrict__ cols,
    const float* __restrict__ vals, int* __restrict__ cur,
    int* __restrict__ cols_s, _Float16* __restrict__ vals_s){
  int i = blockIdx.x*256 + threadIdx.x;
  if(i >= NNZV) return;
  int r = rows[i];
  int j = atomicAdd(&cur[r], 1);
  cols_s[j] = cols[i];
  vals_s[j] = (_Float16)vals[i];
}

// ---------------- feature pack ----------------
// logical cols [0,144): [xp(0..61) | xf(62..98) | pad99 | xn(100..136) | pad..143]
__global__ __launch_bounds__(256) void k_xpack(const float* __restrict__ xp, const float* __restrict__ xf,
    const float* __restrict__ xn, _Float16* __restrict__ xc0, _Float16* __restrict__ xtl){
  int idx = blockIdx.x*256 + threadIdx.x;   // N*18 chunks of 8 cols
  int row = idx/18, c8 = idx - row*18;
  if(row >= Nn) return;
  H4 ha, hb;
  #pragma unroll
  for(int q = 0; q < 8; q++){
    int c = c8*8 + q;
    float x;
    if(c < 62)       x = xp[row*62 + c];
    else if(c < 99)  x = xf[row*37 + (c-62)];
    else if(c == 99) x = 0.f;
    else if(c < 137) x = xn[row*37 + (c-100)];
    else             x = 0.f;
    if(q < 4) ha.h[q] = (_Float16)x; else hb.h[q-4] = (_Float16)x;
  }
  if(c8 < 16){
    *(H4*)&xc0[(size_t)row*128 + c8*8]     = ha;
    *(H4*)&xc0[(size_t)row*128 + c8*8 + 4] = hb;
  } else {
    int t = (c8-16)*8;
    *(H4*)&xtl[(size_t)row*16 + t]     = ha;
    *(H4*)&xtl[(size_t)row*16 + t + 4] = hb;
  }
}

// ---------------- weight pack into MFMA B-fragment order ----------------
// w1frag[v]: [kt(2)][nt(16)][lane(64)][j(8)]; w2frag[v]: [kt(8)][nt(8)][lane(64)][j(8)]
// wdf (decoder): [w(4)][kt(4)][nt(4)][lane(64)][j(8)]
__global__ __launch_bounds__(256) void k_wpackF(
    const float* __restrict__ Wp1, const float* __restrict__ Wf1, const float* __restrict__ Wn1,
    const float* __restrict__ Wp2, const float* __restrict__ Wf2, const float* __restrict__ Wn2,
    const float* __restrict__ Wd1,
    _Float16* __restrict__ w1fp, _Float16* __restrict__ w1ff, _Float16* __restrict__ w1fn,
    _Float16* __restrict__ w2fp, _Float16* __restrict__ w2ff, _Float16* __restrict__ w2fn,
    _Float16* __restrict__ wdf){
  int i = blockIdx.x*256 + threadIdx.x;
  if(i >= 22528) return;
  f16x8 o;
  if(i >= 18432){
    // decoder Wd1 fragments: r = w*1024 + kt*256 + nt*64 + l
    int r = i - 18432;
    int w = r >> 10, kt = (r >> 8) & 3, nt = (r >> 6) & 3, l = r & 63;
    int krow = w*128 + kt*32 + (l>>4)*8, col = nt*16 + (l&15);
    #pragma unroll
    for(int j = 0; j < 8; j++)
      o[j] = (_Float16)Wd1[(krow + j)*64 + col];
    *(f16x8*)&wdf[(size_t)r*8] = o;
    return;
  }
  int v = i / 6144, rem = i - v*6144;
  const float* W1 = (v==0)?Wp1:((v==1)?Wf1:Wn1);
  const float* W2 = (v==0)?Wp2:((v==1)?Wf2:Wn2);
  _Float16* d1 = (v==0)?w1fp:((v==1)?w1ff:w1fn);
  _Float16* d2 = (v==0)?w2fp:((v==1)?w2ff:w2fn);
  int Kv = (v==0)?62:37;
  if(rem < 2048){
    int kt = rem >> 10, r2 = rem & 1023;
    int nt = r2 >> 6, l = r2 & 63;
    int krow = kt*32 + (l>>4)*8, col = nt*16 + (l&15);
    #pragma unroll
    for(int j = 0; j < 8; j++){
      int k = krow + j;
      o[j] = (k < Kv) ? (_Float16)W1[k*256 + col] : (_Float16)0.f;
    }
    *(f16x8*)&d1[rem*8] = o;
  } else {
    int r = rem - 2048;
    int kt = r >> 9, nt = (r >> 6) & 7, l = r & 63;
    int krow = kt*32 + (l>>4)*8, col = nt*16 + (l&15);
    #pragma unroll
    for(int j = 0; j < 8; j++)
      o[j] = (_Float16)W2[(krow + j)*128 + col];
    *(f16x8*)&d2[r*8] = o;
  }
}

// ---------------- gate-score constants: c_v = dot(b2_v, Wg_v) + bg_v ----------------
__global__ void k_const(const float* b2p, const float* Wgp, const float* bgp,
                        const float* b2f, const float* Wgf, const float* bgf,
                        const float* b2n, const float* Wgn, const float* bgn,
                        float* c3){
  int l = threadIdx.x;
  float p = 0.f, f = 0.f, n = 0.f;
  for(int j = l; j < LAT; j += 64){
    p += b2p[j]*Wgp[j];
    f += b2f[j]*Wgf[j];
    n += b2n[j]*Wgn[j];
  }
  #pragma unroll
  for(int off = 32; off >= 1; off >>= 1){
    p += __shfl_xor(p, off);
    f += __shfl_xor(f, off);
    n += __shfl_xor(n, off);
  }
  if(l == 0){ c3[0] = p + bgp[0]; c3[1] = f + bgf[0]; c3[2] = n + bgn[0]; }
}

// ---------------- MFMA encoder view ----------------
__device__ __forceinline__ void encode_view(
    int tid, int row0, int voff, int Kv, int vidx,
    const _Float16 (*sT)[152], _Float16 (*sTv)[72], _Float16 (*hT)[264],
    const _Float16* __restrict__ w1frag, const float* __restrict__ b1,
    const _Float16* __restrict__ w2frag,
    _Float16* __restrict__ Y3){
  int w = tid >> 6, l = tid & 63;
  int kg = l >> 4, er = l & 15;
  int mrow = (w & 1)*16 + er;

  // phase A: aligned, zero-padded A-tile
  {
    int row = tid >> 3, c0 = (tid & 7)*8;
    f16x8 vv;
    #pragma unroll
    for(int q = 0; q < 8; q++){
      int c = c0 + q;
      vv[q] = (c < Kv) ? sT[row][voff + c] : (_Float16)0.f;
    }
    *(f16x8*)&sTv[row][c0] = vv;
  }
  __syncthreads();

  // phase B: G1 = sTv[32x64] @ W1[64x256] -> relu -> hT fp16
  {
    f16x8 a0 = *(const f16x8*)&sTv[mrow][kg*8];
    f16x8 a1 = *(const f16x8*)&sTv[mrow][32 + kg*8];
    int ntb = (w >> 1)*8;
    #pragma unroll
    for(int nt8 = 0; nt8 < 8; nt8++){
      int nt = ntb + nt8;
      f16x8 b0 = *(const f16x8*)&w1frag[(size_t)((0*16 + nt)*64 + l)*8];
      f16x8 b1v = *(const f16x8*)&w1frag[(size_t)((1*16 + nt)*64 + l)*8];
      f32x4 acc = {0.f, 0.f, 0.f, 0.f};
      acc = __builtin_amdgcn_mfma_f32_16x16x32_f16(a0, b0, acc, 0, 0, 0);
      acc = __builtin_amdgcn_mfma_f32_16x16x32_f16(a1, b1v, acc, 0, 0, 0);
      int col = nt*16 + er;
      float bb = b1[col];
      #pragma unroll
      for(int j = 0; j < 4; j++)
        hT[(w & 1)*16 + kg*4 + j][col] = (_Float16)fmaxf(acc[j] + bb, 0.f);
    }
  }
  __syncthreads();

  // phase D: G2 = hT[32x256] @ W2[256x128] -> LDS stage -> Y3 (coalesced 16B stores)
  {
    f16x8 af[8];
    #pragma unroll
    for(int kt = 0; kt < 8; kt++)
      af[kt] = *(const f16x8*)&hT[mrow][kt*32 + kg*8];
    __syncthreads();            // all hT reads done -> hT reusable as Y stage
    _Float16* yst = &hT[0][0];  // viewed as [32][132]
    int ntb = (w >> 1)*4;
    #pragma unroll
    for(int nt4 = 0; nt4 < 4; nt4++){
      int nt = ntb + nt4;
      f32x4 acc = {0.f, 0.f, 0.f, 0.f};
      #pragma unroll
      for(int kt = 0; kt < 8; kt++){
        f16x8 bf = *(const f16x8*)&w2frag[(size_t)((kt*8 + nt)*64 + l)*8];
        acc = __builtin_amdgcn_mfma_f32_16x16x32_f16(af[kt], bf, acc, 0, 0, 0);
      }
      int col = nt*16 + er;
      #pragma unroll
      for(int j = 0; j < 4; j++)
        yst[((w & 1)*16 + kg*4 + j)*132 + col] = (_Float16)acc[j];
    }
    __syncthreads();
    int row = tid >> 3, c0 = (tid & 7)*16;
    f16x8 y0 = *(const f16x8*)&yst[row*132 + c0];
    f16x8 y1 = *(const f16x8*)&yst[row*132 + c0 + 8];
    _Float16* yo = &Y3[(size_t)(row0 + row)*384 + vidx*128 + c0];
    *(f16x8*)yo       = y0;
    *(f16x8*)(yo + 8) = y1;
  }
  __syncthreads();   // hT/sTv reused by next view
}

// ---------------- fused spmm1 (2 rows/wave) + 3 MFMA encoders ----------------
__global__ __launch_bounds__(256, 5) void k_encfused(
    const int* __restrict__ row_ptr, const int* __restrict__ cols_s, const _Float16* __restrict__ vals_s,
    const _Float16* __restrict__ xc0, const _Float16* __restrict__ xtl,
    const _Float16* __restrict__ w1fp, const float* __restrict__ bp1, const _Float16* __restrict__ w2fp,
    const _Float16* __restrict__ w1ff, const float* __restrict__ bf1, const _Float16* __restrict__ w2ff,
    const _Float16* __restrict__ w1fn, const float* __restrict__ bn1, const _Float16* __restrict__ w2fn,
    _Float16* __restrict__ Y3){
  __shared__ _Float16 sT[32][152];   // 9.5 KB
  __shared__ _Float16 sTv[32][72];   // 4.5 KB
  __shared__ _Float16 hT[32][264];   // 16.5 KB (reused as Y stage in phase D)
  int tid = threadIdx.x;
  int lane = tid & 63, wid = tid >> 6;
  int hl = lane & 31;
  int half = lane >> 5;
  int base = lane & 32;
  int row0 = blockIdx.x * 32;
  bool hast = (hl < 4);
  const char* xc0b = (const char*)xc0;
  const char* xtlb = (const char*)xtl;

  // phase 0: gather-spmm, 2 rows per wave (half-wave per row).
  for(int p = 0; p < 4; p++){
    int rr = wid*8 + p*2 + half;
    int r = row0 + rr;
    int start = row_ptr[r], end = row_ptr[r+1];
    int len = end - start;
    int lenO = __shfl(len, lane ^ 32);
    int lenmax = len > lenO ? len : lenO;
    float a0 = 0.f, a1 = 0.f, a2 = 0.f, a3 = 0.f;
    float t0 = 0.f, t1 = 0.f, t2 = 0.f, t3 = 0.f;
    for(int j0 = 0; j0 < lenmax; j0 += 32){
      int m = len - j0; if(m > 32) m = 32; if(m < 0) m = 0;
      int mO = lenO - j0; if(mO > 32) mO = 32; if(mO < 0) mO = 0;
      int mmax = m > mO ? m : mO;
      int mycol = 0; float myval = 0.f;
      if(hl < m){
        mycol = cols_s[start + j0 + hl];
        myval = (float)vals_s[start + j0 + hl];
      }
      int mpad = (mmax + 3) & ~3;
      for(int k = 0; k < mpad; k += 4){
        #pragma unroll
        for(int q = 0; q < 4; q++){
          int c = __shfl(mycol, base + k + q);
          float v = __shfl(myval, base + k + q);
          f16x4 xa = *(const f16x4*)(xc0b + (((unsigned)c) << 8) + hl*8);
          a0 = fmaf((float)xa[0], v, a0);
          a1 = fmaf((float)xa[1], v, a1);
          a2 = fmaf((float)xa[2], v, a2);
          a3 = fmaf((float)xa[3], v, a3);
          if(hast){
            f16x4 xb = *(const f16x4*)(xtlb + ((unsigned)c)*32u + hl*8);
            t0 = fmaf((float)xb[0], v, t0);
            t1 = fmaf((float)xb[1], v, t1);
            t2 = fmaf((float)xb[2], v, t2);
            t3 = fmaf((float)xb[3], v, t3);
          }
        }
      }
    }
    h2 s01; s01[0] = (_Float16)a0; s01[1] = (_Float16)a1;
    h2 s23; s23[0] = (_Float16)a2; s23[1] = (_Float16)a3;
    *(h2*)&sT[rr][4*hl]     = s01;
    *(h2*)&sT[rr][4*hl + 2] = s23;
    if(hast){
      h2 u01; u01[0] = (_Float16)t0; u01[1] = (_Float16)t1;
      h2 u23; u23[0] = (_Float16)t2; u23[1] = (_Float16)t3;
      *(h2*)&sT[rr][128 + 4*hl]     = u01;
      *(h2*)&sT[rr][128 + 4*hl + 2] = u23;
    }
  }
  __syncthreads();

  encode_view(tid, row0, 0,   62, 0, sT, sTv, hT, w1fp, bp1, w2fp, Y3);
  encode_view(tid, row0, 62,  37, 1, sT, sTv, hT, w1ff, bf1, w2ff, Y3);
  encode_view(tid, row0, 100, 37, 2, sT, sTv, hT, w1fn, bn1, w2fn, Y3);
}

// ---------------- fused spmm2 + gate softmax + combine -> z (fp16), 2 rows/wave ----------------
// gate score folded through the accumulators: sc_v = reduce(ap_i * Wg_v[o+i]) + c3[v]
__global__ __launch_bounds__(256, 8) void k_spmm2f(
    const int* __restrict__ row_ptr, const int* __restrict__ cols_s, const _Float16* __restrict__ vals_s,
    const _Float16* __restrict__ Y3,
    const float* __restrict__ Wgp, const float* __restrict__ Wgf, const float* __restrict__ Wgn,
    const float* __restrict__ c3,
    const float* __restrict__ b2p, const float* __restrict__ b2f, const float* __restrict__ b2n,
    _Float16* __restrict__ z){
  int tid = threadIdx.x;
  int lane = tid & 63;
  int hl = lane & 31;
  int half = lane >> 5;
  int base = lane & 32;
  int r = blockIdx.x*8 + (tid >> 6)*2 + half;   // 8 rows/block
  int start = row_ptr[r], end = row_ptr[r+1];
  int len = end - start;
  int lenO = __shfl(len, lane ^ 32);
  int lenmax = len > lenO ? len : lenO;
  unsigned lo = hl*8;                    // byte offset within 256 B view row (4 cols)
  float ap0=0.f, ap1=0.f, ap2=0.f, ap3=0.f;
  float af0=0.f, af1=0.f, af2=0.f, af3=0.f;
  float an0=0.f, an1=0.f, an2=0.f, an3=0.f;
  const char* Yb = (const char*)Y3;
  for(int j0 = 0; j0 < lenmax; j0 += 32){
    int m = len - j0; if(m > 32) m = 32; if(m < 0) m = 0;
    int mO = lenO - j0; if(mO > 32) mO = 32; if(mO < 0) mO = 0;
    int mmax = m > mO ? m : mO;
    int mycol = 0; float myval = 0.f;
    if(hl < m){
      mycol = cols_s[start + j0 + hl];
      myval = (float)vals_s[start + j0 + hl];
    }
    int mpad = (mmax + 3) & ~3;
    for(int k = 0; k < mpad; k += 4){
      #pragma unroll
      for(int q = 0; q < 4; q++){
        int c = __shfl(mycol, base + k + q);
        float v = __shfl(myval, base + k + q);
        const char* p = Yb + ((unsigned)c)*768u + lo;
        f16x4 yp = *(const f16x4*)(p);
        f16x4 yf = *(const f16x4*)(p + 256);
        f16x4 yn = *(const f16x4*)(p + 512);
        ap0 = fmaf((float)yp[0], v, ap0); ap1 = fmaf((float)yp[1], v, ap1);
        ap2 = fmaf((float)yp[2], v, ap2); ap3 = fmaf((float)yp[3], v, ap3);
        af0 = fmaf((float)yf[0], v, af0); af1 = fmaf((float)yf[1], v, af1);
        af2 = fmaf((float)yf[2], v, af2); af3 = fmaf((float)yf[3], v, af3);
        an0 = fmaf((float)yn[0], v, an0); an1 = fmaf((float)yn[1], v, an1);
        an2 = fmaf((float)yn[2], v, an2); an3 = fmaf((float)yn[3], v, an3);
      }
    }
  }
  // gate scores from accumulators (no extra gather): sc_v = (A@Y_v) . Wg_v
  int o = hl*4;
  float4 wp = *(const float4*)&Wgp[o];
  float4 wf = *(const float4*)&Wgf[o];
  float4 wn = *(const float4*)&Wgn[o];
  float scp = ap0*wp.x + ap1*wp.y + ap2*wp.z + ap3*wp.w;
  float scf = af0*wf.x + af1*wf.y + af2*wf.z + af3*wf.w;
  float scn = an0*wn.x + an1*wn.y + an2*wn.z + an3*wn.w;
  #pragma unroll
  for(int off = 16; off >= 1; off >>= 1){
    scp += __shfl_xor(scp, off);
    scf += __shfl_xor(scf, off);
    scn += __shfl_xor(scn, off);
  }
  float sp = scp + c3[0], sf = scf + c3[1], sn = scn + c3[2];
  float mx = fmaxf(sp, fmaxf(sf, sn));
  float ep = expf(sp - mx), ef = expf(sf - mx), en = expf(sn - mx);
  float inv = 1.f / (ep + ef + en);
  float A0 = ep*inv, A1 = ef*inv, A2 = en*inv;
  float4 bp = *(const float4*)&b2p[o];
  float4 bf = *(const float4*)&b2f[o];
  float4 bn = *(const float4*)&b2n[o];
  H4 uz;
  uz.h[0] = (_Float16)(A0*(ap0 + bp.x) + A1*(af0 + bf.x) + A2*(an0 + bn.x));
  uz.h[1] = (_Float16)(A0*(ap1 + bp.y) + A1*(af1 + bf.y) + A2*(an1 + bn.y));
  uz.h[2] = (_Float16)(A0*(ap2 + bp.z) + A1*(af2 + bf.z) + A2*(an2 + bn.z));
  uz.h[3] = (_Float16)(A0*(ap3 + bp.w) + A1*(af3 + bf.w) + A2*(an3 + bn.w));
  *(H4*)&z[(size_t)r*LAT + o] = uz;
}

// ---------------- edge decoder: MFMA, wave = feature region ----------------
// B-fragments streamed from pre-packed wdf (L1/L2-resident) instead of 64 persistent VGPRs.
#define DEC_TILES (NE/16)
__global__ __launch_bounds__(256) void k_dec(
    const _Float16* __restrict__ z, const int* __restrict__ esrc, const int* __restrict__ edst,
    const _Float16* __restrict__ wdf, const float* __restrict__ bd1,
    const float* __restrict__ Wd2, const float* __restrict__ bd2, float* __restrict__ out){
  __shared__ float part[4][16][68];   // 17.4 KB
  int tid = threadIdx.x;
  int w  = tid >> 6;       // wave id = feature region
  int l  = tid & 63;
  int erow = l & 15;
  int kg   = l >> 4;
  const f16x8* wb = (const f16x8*)wdf + (size_t)w*1024 + l;   // frag idx: + kt*256 + nt*64

  int n0 = (tid & 15) * 4;
  int e2 = tid >> 4;
  float4 bb1 = *(const float4*)&bd1[n0];
  float4 w2v = *(const float4*)&Wd2[n0];
  float bias2 = bd2[0];

  for(int tile = blockIdx.x; tile < DEC_TILES; tile += gridDim.x){
    int e = tile*16 + erow;
    int si = esrc[e], di = edst[e];
    const f16x8* zs = (const f16x8*)&z[(size_t)si*LAT];
    const f16x8* zd = (const f16x8*)&z[(size_t)di*LAT];
    f16x8 afr[4];
    if(w == 0){
      #pragma unroll
      for(int kt = 0; kt < 4; kt++) afr[kt] = zs[kt*4 + kg];
    } else if(w == 1){
      #pragma unroll
      for(int kt = 0; kt < 4; kt++) afr[kt] = zd[kt*4 + kg];
    } else if(w == 2){
      #pragma unroll
      for(int kt = 0; kt < 4; kt++) afr[kt] = zs[kt*4 + kg] * zd[kt*4 + kg];
    } else {
      #pragma unroll
      for(int kt = 0; kt < 4; kt++){
        f16x8 d = zs[kt*4 + kg] - zd[kt*4 + kg];
        s16x8 m = __builtin_bit_cast(s16x8, d) & (short)0x7fff;
        afr[kt] = __builtin_bit_cast(f16x8, m);
      }
    }
    f32x4 zero = {0.f, 0.f, 0.f, 0.f};
    f32x4 acc[4] = {zero, zero, zero, zero};
    #pragma unroll
    for(int kt = 0; kt < 4; kt++){
      #pragma unroll
      for(int nt = 0; nt < 4; nt++){
        f16x8 bf = wb[kt*256 + nt*64];
        acc[nt] = __builtin_amdgcn_mfma_f32_16x16x32_f16(afr[kt], bf, acc[nt], 0, 0, 0);
      }
    }
    #pragma unroll
    for(int nt = 0; nt < 4; nt++){
      #pragma unroll
      for(int j = 0; j < 4; j++)
        part[w][kg*4 + j][nt*16 + erow] = acc[nt][j];
    }
    __syncthreads();
    float s0 = part[0][e2][n0+0] + part[1][e2][n0+0] + part[2][e2][n0+0] + part[3][e2][n0+0];
    float s1 = part[0][e2][n0+1] + part[1][e2][n0+1] + part[2][e2][n0+1] + part[3][e2][n0+1];
    float s2 = part[0][e2][n0+2] + part[1][e2][n0+2] + part[2][e2][n0+2] + part[3][e2][n0+2];
    float s3 = part[0][e2][n0+3] + part[1][e2][n0+3] + part[2][e2][n0+3] + part[3][e2][n0+3];
    float p = fmaxf(s0 + bb1.x, 0.f)*w2v.x + fmaxf(s1 + bb1.y, 0.f)*w2v.y
            + fmaxf(s2 + bb1.z, 0.f)*w2v.z + fmaxf(s3 + bb1.w, 0.f)*w2v.w;
    #pragma unroll
    for(int off = 1; off < 16; off <<= 1) p += __shfl_xor(p, off);
    if((tid & 15) == 0) out[tile*16 + e2] = p + bias2;
    __syncthreads();
  }
}

// ---------------- host ----------------
extern "C" void kernel_launch(void* const* d_in, const int* in_sizes, int n_in,
                              void* d_out, int out_size, void* d_ws, size_t ws_size,
                              hipStream_t stream) {
  const float* xp  = (const float*)d_in[0];
  const float* xf  = (const float*)d_in[1];
  const float* xn  = (const float*)d_in[2];
  const int* arows = (const int*)d_in[3];
  const int* acols = (const int*)d_in[4];
  const float* avals = (const float*)d_in[5];
  const int* esrc  = (const int*)d_in[6];
  const int* edst  = (const int*)d_in[7];
  const float* Wp1 = (const float*)d_in[8];  const float* bp1 = (const float*)d_in[9];
  const float* Wp2 = (const float*)d_in[10]; const float* bp2 = (const float*)d_in[11];
  const float* Wf1 = (const float*)d_in[12]; const float* bf1 = (const float*)d_in[13];
  const float* Wf2 = (const float*)d_in[14]; const float* bf2w = (const float*)d_in[15];
  const float* Wn1 = (const float*)d_in[16]; const float* bn1 = (const float*)d_in[17];
  const float* Wn2 = (const float*)d_in[18]; const float* bn2 = (const float*)d_in[19];
  const float* Wgp = (const float*)d_in[20]; const float* bgp = (const float*)d_in[21];
  const float* Wgf = (const float*)d_in[22]; const float* bgf = (const float*)d_in[23];
  const float* Wgn = (const float*)d_in[24]; const float* bgn = (const float*)d_in[25];
  const float* Wd1 = (const float*)d_in[26]; const float* bd1 = (const float*)d_in[27];
  const float* Wd2 = (const float*)d_in[28]; const float* bd2 = (const float*)d_in[29];
  float* out = (float*)d_out;
  (void)in_sizes; (void)n_in; (void)out_size; (void)ws_size;

  char* base = (char*)d_ws;
  size_t off = 0;
  auto alloc = [&](size_t nbytes) -> char* {
    off = (off + 255) & ~(size_t)255;
    char* p = base + off;
    off += nbytes;
    return p;
  };
  int*      row_ptr = (int*)     alloc((size_t)(Nn + 1) * 4);   // 0.8 MB
  int*      cols_s  = (int*)     alloc((size_t)NNZV * 4);       // 25.6 MB
  _Float16* vals_s  = (_Float16*)alloc((size_t)NNZV * 2);       // 12.8 MB
  _Float16* xcat0   = (_Float16*)alloc((size_t)Nn * 128 * 2);   // 51.2 MB
  _Float16* xtail   = (_Float16*)alloc((size_t)Nn * 16 * 2);    // 6.4 MB
  _Float16* Y3      = (_Float16*)alloc((size_t)Nn * 384 * 2);   // 153.6 MB interleaved [N][3][128]
  float*    c3      = (float*)   alloc(256);
  _Float16* w1fp = (_Float16*)alloc(16384*2);
  _Float16* w1ff = (_Float16*)alloc(16384*2);
  _Float16* w1fn = (_Float16*)alloc(16384*2);
  _Float16* w2fp = (_Float16*)alloc(32768*2);
  _Float16* w2ff = (_Float16*)alloc(32768*2);
  _Float16* w2fn = (_Float16*)alloc(32768*2);
  _Float16* wdf  = (_Float16*)alloc(32768*2);   // decoder Wd1 frags, 64 KB
  // z aliases xcat0 (dead after encfused); CSR temps alias xcat0 (dead before k_xpack)
  _Float16* z = xcat0;
  int* cur  = (int*)((char*)xcat0);
  int* incl = (int*)((char*)xcat0 + 1000000);
  int* bsum = (int*)((char*)xcat0 + 2000000);
  // total ws: ~251 MB

  int NB = (Nn + 511) / 512;

  k_zero   <<<(Nn + 255)/256, 256, 0, stream>>>(cur);
  k_count  <<<(NNZV + 255)/256, 256, 0, stream>>>(arows, cur);
  k_scan_block<<<NB, 512, 0, stream>>>(cur, incl, bsum);
  k_scan_bsum<<<1, 512, 0, stream>>>(bsum, NB);
  k_finish <<<(Nn + 255)/256, 256, 0, stream>>>(incl, bsum, row_ptr, cur);
  k_scatter<<<(NNZV + 255)/256, 256, 0, stream>>>(arows, acols, avals, cur, cols_s, vals_s);

  k_xpack<<<(Nn*18 + 255)/256, 256, 0, stream>>>(xp, xf, xn, xcat0, xtail);
  k_wpackF<<<(22528 + 255)/256, 256, 0, stream>>>(Wp1, Wf1, Wn1, Wp2, Wf2, Wn2, Wd1,
                                                  w1fp, w1ff, w1fn, w2fp, w2ff, w2fn, wdf);
  k_const<<<1, 64, 0, stream>>>(bp2, Wgp, bgp, bf2w, Wgf, bgf, bn2, Wgn, bgn, c3);

  k_encfused<<<Nn/32, 256, 0, stream>>>(row_ptr, cols_s, vals_s, xcat0, xtail,
      w1fp, bp1, w2fp,  w1ff, bf1, w2ff,  w1fn, bn1, w2fn,
      Y3);

  k_spmm2f<<<Nn/8, 256, 0, stream>>>(row_ptr, cols_s, vals_s, Y3,
      Wgp, Wgf, Wgn, c3, bp2, bf2w, bn2, z);

  k_dec<<<2048, 256, 0, stream>>>(z, esrc, edst, wdf, bd1, Wd2, bd2, out);
}